// Round 5
// baseline (550.359 us; speedup 1.0000x reference)
//
#include <hip/hip_runtime.h>
#include <hip/hip_bf16.h>

#define NODE_DIM 256
#define COND_DIM 512
#define OUT_DIM  128
#define HID      64
#define LN_EPS   1e-5f

typedef __attribute__((ext_vector_type(8))) short bf16x8;
typedef __attribute__((ext_vector_type(4))) float f32x4;

__device__ __forceinline__ short f2bf(float f) {
    __hip_bfloat16 h = __float2bfloat16(f);
    return *reinterpret_cast<short*>(&h);
}
__device__ __forceinline__ float bf_lo(unsigned int v) {
    union { unsigned int u; float f; } x; x.u = v << 16; return x.f;
}
__device__ __forceinline__ float bf_hi(unsigned int v) {
    union { unsigned int u; float f; } x; x.u = v & 0xffff0000u; return x.f;
}

// ---------------------------------------------------------------------------
// prep (grid 130 x 256):
//  blocks 0..127 : cond projection output o (weight-normed) -> gamma/beta
//  block 128     : weight-norm lin_w_v rows -> wlin_bf [128][64] bf16
//  block 129     : film_w -> fw_bf [64][256] bf16
// ---------------------------------------------------------------------------
__global__ __launch_bounds__(256) void prep(
    const float* __restrict__ cond_feats,
    const float* __restrict__ cond_w_v,
    const float* __restrict__ cond_w_g,
    const float* __restrict__ cond_b,
    const float* __restrict__ lin_w_v,
    const float* __restrict__ lin_w_g,
    const float* __restrict__ film_w,
    float* __restrict__ gamma, float* __restrict__ beta,
    short* __restrict__ wlin_bf, short* __restrict__ fw_bf, int B)
{
    const int t = threadIdx.x;
    const int bid = blockIdx.x;
    if (bid == 128) {
        if (t < OUT_DIM) {
            const int o = t;
            float nrm = 0.f;
            float w[HID];
            #pragma unroll
            for (int k = 0; k < HID; ++k) {
                w[k] = lin_w_v[o * HID + k];
                nrm += w[k] * w[k];
            }
            const float s = lin_w_g[o] * rsqrtf(nrm);
            #pragma unroll
            for (int k = 0; k < HID; ++k) wlin_bf[o * HID + k] = f2bf(w[k] * s);
        }
        return;
    }
    if (bid == 129) {
        for (int idx = t; idx < HID * NODE_DIM; idx += 256)
            fw_bf[idx] = f2bf(film_w[idx]);
        return;
    }
    const int o = bid;
    const int lane = t & 63;
    const int wv = t >> 6;
    __shared__ float s_cp[64];
    __shared__ float s_nrm;
    float wreg[COND_DIM / 64];
    #pragma unroll
    for (int j = 0; j < COND_DIM / 64; ++j)
        wreg[j] = cond_w_v[o * COND_DIM + j * 64 + lane];
    float nr = 0.f;
    #pragma unroll
    for (int j = 0; j < COND_DIM / 64; ++j) nr += wreg[j] * wreg[j];
    #pragma unroll
    for (int off = 32; off > 0; off >>= 1) nr += __shfl_xor(nr, off, 64);
    if (t == 0) s_nrm = nr;
    for (int b = wv; b < 64; b += 4) {
        float a = 0.f;
        #pragma unroll
        for (int j = 0; j < COND_DIM / 64; ++j)
            a += wreg[j] * cond_feats[b * COND_DIM + j * 64 + lane];
        #pragma unroll
        for (int off = 32; off > 0; off >>= 1) a += __shfl_xor(a, off, 64);
        if (lane == 0) s_cp[b] = a;
    }
    __syncthreads();
    if (t < 64) {
        const float scale = cond_w_g[o] * rsqrtf(s_nrm);
        const float cp = scale * s_cp[t] + cond_b[o];
        if (o < HID) gamma[t * HID + o] = cp + 1.0f;
        else         beta[t * HID + (o - HID)] = cp;
    }
}

// ---------------------------------------------------------------------------
// node path via MFMA. Block = 4 waves; wave owns a 16-node strip.
// x_mid written SLICE-MAJOR: [8 slices][N][16 feats] bf16, slice = feat>>4.
// ---------------------------------------------------------------------------
__global__ __launch_bounds__(256) void node_film_mfma(
    const float* __restrict__ nf,
    const short* __restrict__ fw_bf,      // [64 h][256 k]
    const float* __restrict__ film_b,
    const float* __restrict__ lin_b,
    const float* __restrict__ gamma, const float* __restrict__ beta,
    const short* __restrict__ wlin_bf,    // [128 o][64 h]
    const int*  __restrict__ n2g,
    unsigned short* __restrict__ x_mid,   // [8][N][16] bf16 slice-major
    int N)
{
    const int tid = threadIdx.x;
    const int w = tid >> 6;
    const int lane = tid & 63;
    const int c = lane & 15;
    const int quad = lane >> 4;
    const int n0 = blockIdx.x * 64;

    __shared__ float xt[64 * 65];

    // ---- GEMM1: C1[m=16 nodes][n=64 hid], K=256 in 8 steps of 32
    f32x4 c1[4];
    #pragma unroll
    for (int t = 0; t < 4; ++t) { c1[t][0]=0.f; c1[t][1]=0.f; c1[t][2]=0.f; c1[t][3]=0.f; }

    const int mnode = n0 + w * 16 + c;
    const int arow = (mnode < N) ? mnode : (N - 1);
    const float* aptr = nf + (size_t)arow * NODE_DIM + quad * 8;

    #pragma unroll 4
    for (int k0 = 0; k0 < NODE_DIM; k0 += 32) {
        const float4 a01 = *(const float4*)(aptr + k0);
        const float4 a23 = *(const float4*)(aptr + k0 + 4);
        bf16x8 af;
        af[0]=f2bf(a01.x); af[1]=f2bf(a01.y); af[2]=f2bf(a01.z); af[3]=f2bf(a01.w);
        af[4]=f2bf(a23.x); af[5]=f2bf(a23.y); af[6]=f2bf(a23.z); af[7]=f2bf(a23.w);
        #pragma unroll
        for (int nt = 0; nt < 4; ++nt) {
            const bf16x8 bfr = *(const bf16x8*)(fw_bf + ((nt * 16 + c) * NODE_DIM + k0 + quad * 8));
            c1[nt] = __builtin_amdgcn_mfma_f32_16x16x32_bf16(af, bfr, c1[nt], 0, 0, 0);
        }
    }

    #pragma unroll
    for (int nt = 0; nt < 4; ++nt) {
        const float b = film_b[nt * 16 + c];
        c1[nt][0] += b; c1[nt][1] += b; c1[nt][2] += b; c1[nt][3] += b;
    }

    // LN per row; rows = quad*4+r, cols spread over 16 lanes x 4 tiles
    float sum[4], sq[4];
    #pragma unroll
    for (int r = 0; r < 4; ++r) {
        sum[r] = c1[0][r] + c1[1][r] + c1[2][r] + c1[3][r];
        sq[r]  = c1[0][r]*c1[0][r] + c1[1][r]*c1[1][r]
               + c1[2][r]*c1[2][r] + c1[3][r]*c1[3][r];
    }
    #pragma unroll
    for (int off = 1; off < 16; off <<= 1) {
        #pragma unroll
        for (int r = 0; r < 4; ++r) {
            sum[r] += __shfl_xor(sum[r], off, 64);
            sq[r]  += __shfl_xor(sq[r],  off, 64);
        }
    }
    float mu[4], inv[4];
    int gid[4];
    #pragma unroll
    for (int r = 0; r < 4; ++r) {
        mu[r] = sum[r] * (1.0f / HID);
        float var = sq[r] * (1.0f / HID) - mu[r] * mu[r];
        var = fmaxf(var, 0.f);
        inv[r] = rsqrtf(var + LN_EPS);
        const int nn = n0 + w * 16 + quad * 4 + r;
        gid[r] = n2g[(nn < N) ? nn : (N - 1)];
    }

    #pragma unroll
    for (int r = 0; r < 4; ++r) {
        const int row = w * 16 + quad * 4 + r;
        #pragma unroll
        for (int nt = 0; nt < 4; ++nt) {
            const int col = nt * 16 + c;
            const float ga = gamma[gid[r] * HID + col];
            const float be = beta[gid[r] * HID + col];
            float v = ga * ((c1[nt][r] - mu[r]) * inv[r]) + be;
            xt[row * 65 + col] = fmaxf(v, 0.f);
        }
    }
    __syncthreads();

    // ---- GEMM2: C2[m=16 nodes][n=128 out], K=64 in 2 steps of 32
    f32x4 c2[8];
    #pragma unroll
    for (int t = 0; t < 8; ++t) { c2[t][0]=0.f; c2[t][1]=0.f; c2[t][2]=0.f; c2[t][3]=0.f; }

    const int am = w * 16 + c;
    #pragma unroll
    for (int kt = 0; kt < 2; ++kt) {
        const float* xp = xt + am * 65 + kt * 32 + quad * 8;
        bf16x8 af;
        #pragma unroll
        for (int j = 0; j < 8; ++j) af[j] = f2bf(xp[j]);
        #pragma unroll
        for (int nt = 0; nt < 8; ++nt) {
            const bf16x8 bfr = *(const bf16x8*)(wlin_bf + (nt * 16 + c) * HID + kt * 32 + quad * 8);
            c2[nt] = __builtin_amdgcn_mfma_f32_16x16x32_bf16(af, bfr, c2[nt], 0, 0, 0);
        }
    }

    // + lin bias, store bf16 slice-major: slice = nt (feat = nt*16 + c)
    #pragma unroll
    for (int nt = 0; nt < 8; ++nt) {
        const float lb = lin_b[nt * 16 + c];
        #pragma unroll
        for (int r = 0; r < 4; ++r) {
            const int nn = n0 + w * 16 + quad * 4 + r;
            if (nn < N) {
                const short b = f2bf(c2[nt][r] + lb);
                x_mid[(size_t)nt * N * 16 + (size_t)nn * 16 + c] = (unsigned short)b;
            }
        }
    }
}

// ---------------------------------------------------------------------------
// CSR build. deg_count also records each edge's position (epos) so
// bucket_fill needs no atomics.
// ---------------------------------------------------------------------------
__global__ __launch_bounds__(256) void deg_count(
    const int* __restrict__ ei, int* __restrict__ deg,
    int* __restrict__ epos, int E)
{
    const int e = blockIdx.x * 256 + threadIdx.x;
    if (e < E) epos[e] = atomicAdd(&deg[ei[E + e]], 1);
}

__global__ __launch_bounds__(1024) void scan1(
    const int* __restrict__ deg, int* __restrict__ csr_off,
    int* __restrict__ bsums, int N)
{
    __shared__ int s[1024];
    const int t = threadIdx.x;
    const int i = blockIdx.x * 1024 + t;
    s[t] = (i < N) ? deg[i] : 0;
    __syncthreads();
    for (int off = 1; off < 1024; off <<= 1) {
        const int x = s[t];
        const int y = (t >= off) ? s[t - off] : 0;
        __syncthreads();
        s[t] = x + y;
        __syncthreads();
    }
    if (i < N) csr_off[i + 1] = s[t];
    if (t == 1023) bsums[blockIdx.x] = s[1023];
}

__global__ __launch_bounds__(1024) void scan2(
    const int* __restrict__ bsums, int* __restrict__ boff, int NB)
{
    __shared__ int s[1024];
    const int t = threadIdx.x;
    const int v = (t < NB) ? bsums[t] : 0;
    s[t] = v;
    __syncthreads();
    for (int off = 1; off < 1024; off <<= 1) {
        const int x = s[t];
        const int y = (t >= off) ? s[t - off] : 0;
        __syncthreads();
        s[t] = x + y;
        __syncthreads();
    }
    if (t < NB) boff[t] = s[t] - v;  // exclusive
}

__global__ __launch_bounds__(1024) void scan3(
    int* __restrict__ csr_off, const int* __restrict__ boff, int N)
{
    const int i = blockIdx.x * 1024 + threadIdx.x;
    if (i < N) csr_off[i + 1] += boff[blockIdx.x];
    if (i == 0) csr_off[0] = 0;
}

__global__ __launch_bounds__(256) void bucket_fill(
    const int* __restrict__ ei, const int* __restrict__ csr_off,
    const int* __restrict__ epos, int* __restrict__ bucket_src, int E)
{
    const int e = blockIdx.x * 256 + threadIdx.x;
    if (e >= E) return;
    const int src = ei[e];
    const int dst = ei[E + e];
    bucket_src[csr_off[dst] + epos[e]] = src;
}

// ---------------------------------------------------------------------------
// gather-reduce, feature-sliced + XCD-affine. slice = blockIdx.x & 7 (HW
// round-robin block->XCD => slice s resident on XCD s; slice region = N*32B
// = 3.2MB fits one XCD L2). Wave: 8 edges x 8 lanes (lane = uint of 2 feats,
// 32B contiguous per edge). Each wave handles 8 dsts sequentially.
// ---------------------------------------------------------------------------
__global__ __launch_bounds__(256) void edge_aggregate(
    const int* __restrict__ csr_off, const int* __restrict__ bucket_src,
    const unsigned int* __restrict__ xm,   // [8][N][8] uints, slice-major
    float* __restrict__ out, int N)
{
    const int slice = blockIdx.x & 7;
    const int lane = threadIdx.x & 63;
    const int u = lane & 7;       // uint index within slice (2 feats)
    const int eo = lane >> 3;     // edge slot 0..7
    const int d0 = (blockIdx.x >> 3) * 32 + (threadIdx.x >> 6) * 8;
    const unsigned int* xs = xm + (size_t)slice * N * 8;

    #pragma unroll 1
    for (int i = 0; i < 8; ++i) {
        const int dst = d0 + i;
        if (dst >= N) return;
        const int base = csr_off[dst];
        const int end  = csr_off[dst + 1];
        float a0 = 0.f, a1 = 0.f;
        for (int p = base; p < end; p += 8) {
            const int e = p + eo;
            const int src = bucket_src[(e < end) ? e : (end - 1)];
            const unsigned int v = xs[(size_t)src * 8 + u];
            const float m = (e < end) ? 1.f : 0.f;
            a0 += m * bf_lo(v);
            a1 += m * bf_hi(v);
        }
        a0 += __shfl_xor(a0, 8, 64);  a1 += __shfl_xor(a1, 8, 64);
        a0 += __shfl_xor(a0, 16, 64); a1 += __shfl_xor(a1, 16, 64);
        a0 += __shfl_xor(a0, 32, 64); a1 += __shfl_xor(a1, 32, 64);
        if (lane < 8) {
            const float d = fmaxf((float)(end - base), 1.f);
            float2 o;
            o.x = fmaxf(a0 / d, 0.f);
            o.y = fmaxf(a1 / d, 0.f);
            *(float2*)(out + (size_t)dst * OUT_DIM + slice * 16 + lane * 2) = o;
        }
    }
}

extern "C" void kernel_launch(void* const* d_in, const int* in_sizes, int n_in,
                              void* d_out, int out_size, void* d_ws, size_t ws_size,
                              hipStream_t stream) {
    const float* node_feats = (const float*)d_in[0];
    const float* cond_feats = (const float*)d_in[1];
    const float* cond_w_v   = (const float*)d_in[2];
    const float* cond_w_g   = (const float*)d_in[3];
    const float* cond_b     = (const float*)d_in[4];
    const float* film_w     = (const float*)d_in[5];
    const float* film_b     = (const float*)d_in[6];
    const float* lin_w_v    = (const float*)d_in[7];
    const float* lin_w_g    = (const float*)d_in[8];
    const float* lin_b      = (const float*)d_in[9];
    const int* edge_index   = (const int*)d_in[10];
    const int* node2graph   = (const int*)d_in[11];

    const int N = in_sizes[0] / NODE_DIM;     // 100000
    const int B = in_sizes[1] / COND_DIM;     // 64
    const int E = in_sizes[10] / 2;           // 1600000
    const int NB = (N + 1023) / 1024;

    auto align_up = [](size_t x) { return (x + 255) & ~(size_t)255; };
    char* ws = (char*)d_ws;
    size_t off = 0;
    int* deg        = (int*)(ws + off); off += align_up((size_t)N * 4);
    const size_t zero_bytes = off;            // deg zeroed
    int* csr_off    = (int*)(ws + off); off += align_up((size_t)(N + 1) * 4);
    int* bsums      = (int*)(ws + off); off += align_up(1024 * 4);
    int* boff       = (int*)(ws + off); off += align_up(1024 * 4);
    int* epos       = (int*)(ws + off); off += align_up((size_t)E * 4);
    int* bucket_src = (int*)(ws + off); off += align_up((size_t)E * 4);
    unsigned short* x_mid = (unsigned short*)(ws + off); off += align_up((size_t)N * OUT_DIM * 2);
    float* gamma    = (float*)(ws + off); off += align_up((size_t)B * HID * 4);
    float* beta     = (float*)(ws + off); off += align_up((size_t)B * HID * 4);
    short* wlin_bf  = (short*)(ws + off); off += align_up((size_t)OUT_DIM * HID * 2);
    short* fw_bf    = (short*)(ws + off); off += align_up((size_t)HID * NODE_DIM * 2);

    hipMemsetAsync(d_ws, 0, zero_bytes, stream);

    prep<<<130, 256, 0, stream>>>(cond_feats, cond_w_v, cond_w_g, cond_b,
                                  lin_w_v, lin_w_g, film_w,
                                  gamma, beta, wlin_bf, fw_bf, B);

    deg_count<<<(E + 255) / 256, 256, 0, stream>>>(edge_index, deg, epos, E);
    scan1<<<NB, 1024, 0, stream>>>(deg, csr_off, bsums, N);
    scan2<<<1, 1024, 0, stream>>>(bsums, boff, NB);
    scan3<<<NB, 1024, 0, stream>>>(csr_off, boff, N);
    bucket_fill<<<(E + 255) / 256, 256, 0, stream>>>(edge_index, csr_off,
                                                     epos, bucket_src, E);

    node_film_mfma<<<(N + 63) / 64, 256, 0, stream>>>(
        node_feats, fw_bf, film_b, lin_b, gamma, beta, wlin_bf, node2graph,
        x_mid, N);

    edge_aggregate<<<((N + 31) / 32) * 8, 256, 0, stream>>>(
        csr_off, bucket_src, (const unsigned int*)x_mid, (float*)d_out, N);
}

// Round 6
// 405.152 us; speedup vs baseline: 1.3584x; 1.3584x over previous
//
#include <hip/hip_runtime.h>
#include <hip/hip_bf16.h>

#define NODE_DIM 256
#define COND_DIM 512
#define OUT_DIM  128
#define HID      64
#define LN_EPS   1e-5f

typedef __attribute__((ext_vector_type(8))) short bf16x8;
typedef __attribute__((ext_vector_type(4))) float f32x4;

__device__ __forceinline__ short f2bf(float f) {
    __hip_bfloat16 h = __float2bfloat16(f);
    return *reinterpret_cast<short*>(&h);
}
__device__ __forceinline__ float bf_lo(unsigned int v) {
    union { unsigned int u; float f; } x; x.u = v << 16; return x.f;
}
__device__ __forceinline__ float bf_hi(unsigned int v) {
    union { unsigned int u; float f; } x; x.u = v & 0xffff0000u; return x.f;
}

// ---------------------------------------------------------------------------
// prep (grid 130 x 256):
//  blocks 0..127 : cond projection output o (weight-normed) -> gamma/beta
//  block 128     : weight-norm lin_w_v rows -> wlin_bf [128 o][64 k] bf16
//  block 129     : film_w -> fw_bf [64 h][256 k] bf16
// ---------------------------------------------------------------------------
__global__ __launch_bounds__(256) void prep(
    const float* __restrict__ cond_feats,
    const float* __restrict__ cond_w_v,
    const float* __restrict__ cond_w_g,
    const float* __restrict__ cond_b,
    const float* __restrict__ lin_w_v,
    const float* __restrict__ lin_w_g,
    const float* __restrict__ film_w,
    float* __restrict__ gamma, float* __restrict__ beta,
    short* __restrict__ wlin_bf, short* __restrict__ fw_bf, int B)
{
    const int t = threadIdx.x;
    const int bid = blockIdx.x;
    if (bid == 128) {
        if (t < OUT_DIM) {
            const int o = t;
            float nrm = 0.f;
            float w[HID];
            #pragma unroll
            for (int k = 0; k < HID; ++k) {
                w[k] = lin_w_v[o * HID + k];
                nrm += w[k] * w[k];
            }
            const float s = lin_w_g[o] * rsqrtf(nrm);
            #pragma unroll
            for (int k = 0; k < HID; ++k) wlin_bf[o * HID + k] = f2bf(w[k] * s);
        }
        return;
    }
    if (bid == 129) {
        for (int idx = t; idx < HID * NODE_DIM; idx += 256)
            fw_bf[idx] = f2bf(film_w[idx]);
        return;
    }
    const int o = bid;
    const int lane = t & 63;
    const int wv = t >> 6;
    __shared__ float s_cp[64];
    __shared__ float s_nrm;
    float wreg[COND_DIM / 64];
    #pragma unroll
    for (int j = 0; j < COND_DIM / 64; ++j)
        wreg[j] = cond_w_v[o * COND_DIM + j * 64 + lane];
    float nr = 0.f;
    #pragma unroll
    for (int j = 0; j < COND_DIM / 64; ++j) nr += wreg[j] * wreg[j];
    #pragma unroll
    for (int off = 32; off > 0; off >>= 1) nr += __shfl_xor(nr, off, 64);
    if (t == 0) s_nrm = nr;
    for (int b = wv; b < 64; b += 4) {
        float a = 0.f;
        #pragma unroll
        for (int j = 0; j < COND_DIM / 64; ++j)
            a += wreg[j] * cond_feats[b * COND_DIM + j * 64 + lane];
        #pragma unroll
        for (int off = 32; off > 0; off >>= 1) a += __shfl_xor(a, off, 64);
        if (lane == 0) s_cp[b] = a;
    }
    __syncthreads();
    if (t < 64) {
        const float scale = cond_w_g[o] * rsqrtf(s_nrm);
        const float cp = scale * s_cp[t] + cond_b[o];
        if (o < HID) gamma[t * HID + o] = cp + 1.0f;
        else         beta[t * HID + (o - HID)] = cp;
    }
}

// ---------------------------------------------------------------------------
// node path: GEMM1 + LN + FiLM + relu -> h bf16 [N][64] (128 B rows = 1 line).
// Block = 4 waves; wave owns a 16-node strip. No LDS needed.
// ---------------------------------------------------------------------------
__global__ __launch_bounds__(256) void node_film_h(
    const float* __restrict__ nf,
    const short* __restrict__ fw_bf,      // [64 h][256 k]
    const float* __restrict__ film_b,
    const float* __restrict__ gamma, const float* __restrict__ beta,
    const int*  __restrict__ n2g,
    unsigned short* __restrict__ h_out,   // [N][64] bf16
    int N)
{
    const int tid = threadIdx.x;
    const int w = tid >> 6;
    const int lane = tid & 63;
    const int c = lane & 15;
    const int quad = lane >> 4;
    const int n0 = blockIdx.x * 64;

    // ---- GEMM1: C1[m=16 nodes][n=64 hid], K=256 in 8 steps of 32
    f32x4 c1[4];
    #pragma unroll
    for (int t = 0; t < 4; ++t) { c1[t][0]=0.f; c1[t][1]=0.f; c1[t][2]=0.f; c1[t][3]=0.f; }

    const int mnode = n0 + w * 16 + c;
    const int arow = (mnode < N) ? mnode : (N - 1);
    const float* aptr = nf + (size_t)arow * NODE_DIM + quad * 8;

    #pragma unroll 4
    for (int k0 = 0; k0 < NODE_DIM; k0 += 32) {
        const float4 a01 = *(const float4*)(aptr + k0);
        const float4 a23 = *(const float4*)(aptr + k0 + 4);
        bf16x8 af;
        af[0]=f2bf(a01.x); af[1]=f2bf(a01.y); af[2]=f2bf(a01.z); af[3]=f2bf(a01.w);
        af[4]=f2bf(a23.x); af[5]=f2bf(a23.y); af[6]=f2bf(a23.z); af[7]=f2bf(a23.w);
        #pragma unroll
        for (int nt = 0; nt < 4; ++nt) {
            const bf16x8 bfr = *(const bf16x8*)(fw_bf + ((nt * 16 + c) * NODE_DIM + k0 + quad * 8));
            c1[nt] = __builtin_amdgcn_mfma_f32_16x16x32_bf16(af, bfr, c1[nt], 0, 0, 0);
        }
    }

    #pragma unroll
    for (int nt = 0; nt < 4; ++nt) {
        const float b = film_b[nt * 16 + c];
        c1[nt][0] += b; c1[nt][1] += b; c1[nt][2] += b; c1[nt][3] += b;
    }

    // LN per row (node): row = quad*4 + r, cols spread over 16 lanes x 4 tiles
    float sum[4], sq[4];
    #pragma unroll
    for (int r = 0; r < 4; ++r) {
        sum[r] = c1[0][r] + c1[1][r] + c1[2][r] + c1[3][r];
        sq[r]  = c1[0][r]*c1[0][r] + c1[1][r]*c1[1][r]
               + c1[2][r]*c1[2][r] + c1[3][r]*c1[3][r];
    }
    #pragma unroll
    for (int off = 1; off < 16; off <<= 1) {
        #pragma unroll
        for (int r = 0; r < 4; ++r) {
            sum[r] += __shfl_xor(sum[r], off, 64);
            sq[r]  += __shfl_xor(sq[r],  off, 64);
        }
    }
    float mu[4], inv[4];
    int gid[4];
    #pragma unroll
    for (int r = 0; r < 4; ++r) {
        mu[r] = sum[r] * (1.0f / HID);
        float var = sq[r] * (1.0f / HID) - mu[r] * mu[r];
        var = fmaxf(var, 0.f);
        inv[r] = rsqrtf(var + LN_EPS);
        const int nn = n0 + w * 16 + quad * 4 + r;
        gid[r] = n2g[(nn < N) ? nn : (N - 1)];
    }

    // FiLM + relu -> h bf16 store
    #pragma unroll
    for (int r = 0; r < 4; ++r) {
        const int nn = n0 + w * 16 + quad * 4 + r;
        if (nn >= N) continue;
        #pragma unroll
        for (int nt = 0; nt < 4; ++nt) {
            const int col = nt * 16 + c;
            const float ga = gamma[gid[r] * HID + col];
            const float be = beta[gid[r] * HID + col];
            const float v = fmaxf(ga * ((c1[nt][r] - mu[r]) * inv[r]) + be, 0.f);
            h_out[(size_t)nn * HID + col] = (unsigned short)f2bf(v);
        }
    }
}

// ---------------------------------------------------------------------------
// CSR build (epos from deg_count -> atomic-free bucket_fill)
// ---------------------------------------------------------------------------
__global__ __launch_bounds__(256) void deg_count(
    const int* __restrict__ ei, int* __restrict__ deg,
    int* __restrict__ epos, int E)
{
    const int e = blockIdx.x * 256 + threadIdx.x;
    if (e < E) epos[e] = atomicAdd(&deg[ei[E + e]], 1);
}

__global__ __launch_bounds__(1024) void scan1(
    const int* __restrict__ deg, int* __restrict__ csr_off,
    int* __restrict__ bsums, int N)
{
    __shared__ int s[1024];
    const int t = threadIdx.x;
    const int i = blockIdx.x * 1024 + t;
    s[t] = (i < N) ? deg[i] : 0;
    __syncthreads();
    for (int off = 1; off < 1024; off <<= 1) {
        const int x = s[t];
        const int y = (t >= off) ? s[t - off] : 0;
        __syncthreads();
        s[t] = x + y;
        __syncthreads();
    }
    if (i < N) csr_off[i + 1] = s[t];
    if (t == 1023) bsums[blockIdx.x] = s[1023];
}

__global__ __launch_bounds__(1024) void scan2(
    const int* __restrict__ bsums, int* __restrict__ boff, int NB)
{
    __shared__ int s[1024];
    const int t = threadIdx.x;
    const int v = (t < NB) ? bsums[t] : 0;
    s[t] = v;
    __syncthreads();
    for (int off = 1; off < 1024; off <<= 1) {
        const int x = s[t];
        const int y = (t >= off) ? s[t - off] : 0;
        __syncthreads();
        s[t] = x + y;
        __syncthreads();
    }
    if (t < NB) boff[t] = s[t] - v;  // exclusive
}

__global__ __launch_bounds__(1024) void scan3(
    int* __restrict__ csr_off, const int* __restrict__ boff, int N)
{
    const int i = blockIdx.x * 1024 + threadIdx.x;
    if (i < N) csr_off[i + 1] += boff[blockIdx.x];
    if (i == 0) csr_off[0] = 0;
}

__global__ __launch_bounds__(256) void bucket_fill(
    const int* __restrict__ ei, const int* __restrict__ csr_off,
    const int* __restrict__ epos, int* __restrict__ bucket_src, int E)
{
    const int e = blockIdx.x * 256 + threadIdx.x;
    if (e >= E) return;
    bucket_src[csr_off[ei[E + e]] + epos[e]] = ei[e];
}

// ---------------------------------------------------------------------------
// gather-reduce over h rows (128 B = exactly 1 L2 line, fully used).
// Wave: 2 edges x 32 lanes (lane = uint of 2 feats); 4 double-edge loads in
// flight per step; shfl_xor(32) merges the two edge slots. Writes mean_h fp32.
// ---------------------------------------------------------------------------
__global__ __launch_bounds__(256) void edge_aggregate_h(
    const int* __restrict__ csr_off, const int* __restrict__ bucket_src,
    const unsigned int* __restrict__ h,   // [N][32] uints
    float* __restrict__ mean_h, int N)
{
    const int lane = threadIdx.x & 63;
    const int u = lane & 31;      // uint index (2 feats)
    const int eo = lane >> 5;     // edge slot 0..1
    const int d0 = blockIdx.x * 32 + (threadIdx.x >> 6) * 8;

    #pragma unroll 1
    for (int i = 0; i < 8; ++i) {
        const int dst = d0 + i;
        if (dst >= N) return;
        const int base = csr_off[dst];
        const int end  = csr_off[dst + 1];
        float a0 = 0.f, a1 = 0.f;
        for (int p = base; p < end; p += 8) {
            const int e0 = p + eo;
            const int e1 = e0 + 2;
            const int e2 = e0 + 4;
            const int e3 = e0 + 6;
            const int s0 = bucket_src[(e0 < end) ? e0 : (end - 1)];
            const int s1 = bucket_src[(e1 < end) ? e1 : (end - 1)];
            const int s2 = bucket_src[(e2 < end) ? e2 : (end - 1)];
            const int s3 = bucket_src[(e3 < end) ? e3 : (end - 1)];
            const unsigned int v0 = h[(size_t)s0 * 32 + u];
            const unsigned int v1 = h[(size_t)s1 * 32 + u];
            const unsigned int v2 = h[(size_t)s2 * 32 + u];
            const unsigned int v3 = h[(size_t)s3 * 32 + u];
            const float m0 = (e0 < end) ? 1.f : 0.f;
            const float m1 = (e1 < end) ? 1.f : 0.f;
            const float m2 = (e2 < end) ? 1.f : 0.f;
            const float m3 = (e3 < end) ? 1.f : 0.f;
            a0 += m0 * bf_lo(v0) + m1 * bf_lo(v1) + m2 * bf_lo(v2) + m3 * bf_lo(v3);
            a1 += m0 * bf_hi(v0) + m1 * bf_hi(v1) + m2 * bf_hi(v2) + m3 * bf_hi(v3);
        }
        a0 += __shfl_xor(a0, 32, 64);
        a1 += __shfl_xor(a1, 32, 64);
        if (lane < 32) {
            const float d = fmaxf((float)(end - base), 1.f);
            float2 o;
            o.x = a0 / d;
            o.y = a1 / d;
            *(float2*)(mean_h + (size_t)dst * HID + u * 2) = o;
        }
    }
}

// ---------------------------------------------------------------------------
// final linear via MFMA: out = relu(mean_h @ wlinT + lin_b), 0 where deg==0.
// Block = 4 waves; wave owns 16-node strip, full 128 outputs.
// ---------------------------------------------------------------------------
__global__ __launch_bounds__(256) void final_linear(
    const float* __restrict__ mean_h,     // [N][64]
    const short* __restrict__ wlin_bf,    // [128 o][64 k]
    const float* __restrict__ lin_b,
    const int*  __restrict__ csr_off,
    float* __restrict__ out, int N)
{
    const int tid = threadIdx.x;
    const int w = tid >> 6;
    const int lane = tid & 63;
    const int c = lane & 15;
    const int quad = lane >> 4;
    const int n0 = blockIdx.x * 64;

    const int mnode = n0 + w * 16 + c;
    const int arow = (mnode < N) ? mnode : (N - 1);
    const float* aptr = mean_h + (size_t)arow * HID + quad * 8;

    f32x4 c2[8];
    #pragma unroll
    for (int t = 0; t < 8; ++t) { c2[t][0]=0.f; c2[t][1]=0.f; c2[t][2]=0.f; c2[t][3]=0.f; }

    #pragma unroll
    for (int kt = 0; kt < 2; ++kt) {
        const float4 a01 = *(const float4*)(aptr + kt * 32);
        const float4 a23 = *(const float4*)(aptr + kt * 32 + 4);
        bf16x8 af;
        af[0]=f2bf(a01.x); af[1]=f2bf(a01.y); af[2]=f2bf(a01.z); af[3]=f2bf(a01.w);
        af[4]=f2bf(a23.x); af[5]=f2bf(a23.y); af[6]=f2bf(a23.z); af[7]=f2bf(a23.w);
        #pragma unroll
        for (int nt = 0; nt < 8; ++nt) {
            const bf16x8 bfr = *(const bf16x8*)(wlin_bf + (nt * 16 + c) * HID + kt * 32 + quad * 8);
            c2[nt] = __builtin_amdgcn_mfma_f32_16x16x32_bf16(af, bfr, c2[nt], 0, 0, 0);
        }
    }

    // per C-row deg mask (rows = quad*4+r)
    float mask[4];
    #pragma unroll
    for (int r = 0; r < 4; ++r) {
        const int nn = n0 + w * 16 + quad * 4 + r;
        const int nc = (nn < N) ? nn : (N - 1);
        mask[r] = (csr_off[nc + 1] - csr_off[nc] > 0) ? 1.f : 0.f;
    }

    #pragma unroll
    for (int nt = 0; nt < 8; ++nt) {
        const float lb = lin_b[nt * 16 + c];
        #pragma unroll
        for (int r = 0; r < 4; ++r) {
            const int nn = n0 + w * 16 + quad * 4 + r;
            if (nn < N)
                out[(size_t)nn * OUT_DIM + nt * 16 + c] =
                    mask[r] * fmaxf(c2[nt][r] + lb, 0.f);
        }
    }
}

extern "C" void kernel_launch(void* const* d_in, const int* in_sizes, int n_in,
                              void* d_out, int out_size, void* d_ws, size_t ws_size,
                              hipStream_t stream) {
    const float* node_feats = (const float*)d_in[0];
    const float* cond_feats = (const float*)d_in[1];
    const float* cond_w_v   = (const float*)d_in[2];
    const float* cond_w_g   = (const float*)d_in[3];
    const float* cond_b     = (const float*)d_in[4];
    const float* film_w     = (const float*)d_in[5];
    const float* film_b     = (const float*)d_in[6];
    const float* lin_w_v    = (const float*)d_in[7];
    const float* lin_w_g    = (const float*)d_in[8];
    const float* lin_b      = (const float*)d_in[9];
    const int* edge_index   = (const int*)d_in[10];
    const int* node2graph   = (const int*)d_in[11];

    const int N = in_sizes[0] / NODE_DIM;     // 100000
    const int B = in_sizes[1] / COND_DIM;     // 64
    const int E = in_sizes[10] / 2;           // 1600000
    const int NB = (N + 1023) / 1024;

    auto align_up = [](size_t x) { return (x + 255) & ~(size_t)255; };
    char* ws = (char*)d_ws;
    size_t off = 0;
    int* deg        = (int*)(ws + off); off += align_up((size_t)N * 4);
    const size_t zero_bytes = off;            // deg zeroed
    int* csr_off    = (int*)(ws + off); off += align_up((size_t)(N + 1) * 4);
    int* bsums      = (int*)(ws + off); off += align_up(1024 * 4);
    int* boff       = (int*)(ws + off); off += align_up(1024 * 4);
    int* epos       = (int*)(ws + off); off += align_up((size_t)E * 4);
    int* bucket_src = (int*)(ws + off); off += align_up((size_t)E * 4);
    unsigned short* h_buf = (unsigned short*)(ws + off); off += align_up((size_t)N * HID * 2);
    float* mean_h   = (float*)(ws + off); off += align_up((size_t)N * HID * 4);
    float* gamma    = (float*)(ws + off); off += align_up((size_t)B * HID * 4);
    float* beta     = (float*)(ws + off); off += align_up((size_t)B * HID * 4);
    short* wlin_bf  = (short*)(ws + off); off += align_up((size_t)OUT_DIM * HID * 2);
    short* fw_bf    = (short*)(ws + off); off += align_up((size_t)HID * NODE_DIM * 2);

    hipMemsetAsync(d_ws, 0, zero_bytes, stream);

    prep<<<130, 256, 0, stream>>>(cond_feats, cond_w_v, cond_w_g, cond_b,
                                  lin_w_v, lin_w_g, film_w,
                                  gamma, beta, wlin_bf, fw_bf, B);

    deg_count<<<(E + 255) / 256, 256, 0, stream>>>(edge_index, deg, epos, E);
    scan1<<<NB, 1024, 0, stream>>>(deg, csr_off, bsums, N);
    scan2<<<1, 1024, 0, stream>>>(bsums, boff, NB);
    scan3<<<NB, 1024, 0, stream>>>(csr_off, boff, N);
    bucket_fill<<<(E + 255) / 256, 256, 0, stream>>>(edge_index, csr_off,
                                                     epos, bucket_src, E);

    node_film_h<<<(N + 63) / 64, 256, 0, stream>>>(
        node_feats, fw_bf, film_b, gamma, beta, node2graph, h_buf, N);

    edge_aggregate_h<<<(N + 31) / 32, 256, 0, stream>>>(
        csr_off, bucket_src, (const unsigned int*)h_buf, mean_h, N);

    final_linear<<<(N + 63) / 64, 256, 0, stream>>>(
        mean_h, wlin_bf, lin_b, csr_off, (float*)d_out, N);
}

// Round 7
// 368.480 us; speedup vs baseline: 1.4936x; 1.0995x over previous
//
#include <hip/hip_runtime.h>
#include <hip/hip_bf16.h>

#define NODE_DIM 256
#define COND_DIM 512
#define OUT_DIM  128
#define HID      64
#define LN_EPS   1e-5f

typedef __attribute__((ext_vector_type(8))) short bf16x8;
typedef __attribute__((ext_vector_type(4))) float f32x4;

__device__ __forceinline__ short f2bf(float f) {
    __hip_bfloat16 h = __float2bfloat16(f);
    return *reinterpret_cast<short*>(&h);
}
__device__ __forceinline__ float bf_lo(unsigned int v) {
    union { unsigned int u; float f; } x; x.u = v << 16; return x.f;
}
__device__ __forceinline__ float bf_hi(unsigned int v) {
    union { unsigned int u; float f; } x; x.u = v & 0xffff0000u; return x.f;
}

// ---------------------------------------------------------------------------
// prep (grid 130 + zero-blocks):
//  blocks 0..127 : cond projection output o (weight-normed) -> gamma/beta
//  block 128     : weight-norm lin_w_v rows -> wlin_bf [128 o][64 k] bf16
//  block 129     : film_w -> fw_bf [64 h][256 k] bf16
//  blocks 130+   : zero deg[] (replaces hipMemsetAsync launch)
// ---------------------------------------------------------------------------
__global__ __launch_bounds__(256) void prep(
    const float* __restrict__ cond_feats,
    const float* __restrict__ cond_w_v,
    const float* __restrict__ cond_w_g,
    const float* __restrict__ cond_b,
    const float* __restrict__ lin_w_v,
    const float* __restrict__ lin_w_g,
    const float* __restrict__ film_w,
    float* __restrict__ gamma, float* __restrict__ beta,
    short* __restrict__ wlin_bf, short* __restrict__ fw_bf,
    int* __restrict__ deg, int N, int B)
{
    const int t = threadIdx.x;
    const int bid = blockIdx.x;
    if (bid >= 130) {
        const int z = bid - 130;
        const int i0 = z * 1024 + t * 4;
        #pragma unroll
        for (int j = 0; j < 4; ++j)
            if (i0 + j < N) deg[i0 + j] = 0;
        return;
    }
    if (bid == 128) {
        if (t < OUT_DIM) {
            const int o = t;
            float nrm = 0.f;
            float w[HID];
            #pragma unroll
            for (int k = 0; k < HID; ++k) {
                w[k] = lin_w_v[o * HID + k];
                nrm += w[k] * w[k];
            }
            const float s = lin_w_g[o] * rsqrtf(nrm);
            #pragma unroll
            for (int k = 0; k < HID; ++k) wlin_bf[o * HID + k] = f2bf(w[k] * s);
        }
        return;
    }
    if (bid == 129) {
        for (int idx = t; idx < HID * NODE_DIM; idx += 256)
            fw_bf[idx] = f2bf(film_w[idx]);
        return;
    }
    const int o = bid;
    const int lane = t & 63;
    const int wv = t >> 6;
    __shared__ float s_cp[64];
    __shared__ float s_nrm;
    float wreg[COND_DIM / 64];
    #pragma unroll
    for (int j = 0; j < COND_DIM / 64; ++j)
        wreg[j] = cond_w_v[o * COND_DIM + j * 64 + lane];
    float nr = 0.f;
    #pragma unroll
    for (int j = 0; j < COND_DIM / 64; ++j) nr += wreg[j] * wreg[j];
    #pragma unroll
    for (int off = 32; off > 0; off >>= 1) nr += __shfl_xor(nr, off, 64);
    if (t == 0) s_nrm = nr;
    for (int b = wv; b < 64; b += 4) {
        float a = 0.f;
        #pragma unroll
        for (int j = 0; j < COND_DIM / 64; ++j)
            a += wreg[j] * cond_feats[b * COND_DIM + j * 64 + lane];
        #pragma unroll
        for (int off = 32; off > 0; off >>= 1) a += __shfl_xor(a, off, 64);
        if (lane == 0) s_cp[b] = a;
    }
    __syncthreads();
    if (t < 64) {
        const float scale = cond_w_g[o] * rsqrtf(s_nrm);
        const float cp = scale * s_cp[t] + cond_b[o];
        if (o < HID) gamma[t * HID + o] = cp + 1.0f;
        else         beta[t * HID + (o - HID)] = cp;
    }
}

// ---------------------------------------------------------------------------
// fused_phase1: deg_count (atomic histogram + epos) interleaved with the
// node FiLM path (GEMM1 + LN + FiLM + relu -> h bf16 [N][64]).
// Independent work; deg's atomic-latency stalls hide behind film's
// MFMA/stream busy waves (time ~ max, not sum). Block pattern d,f,f.
// ---------------------------------------------------------------------------
__global__ __launch_bounds__(256) void fused_phase1(
    const float* __restrict__ nf,
    const short* __restrict__ fw_bf,      // [64 h][256 k]
    const float* __restrict__ film_b,
    const float* __restrict__ gamma, const float* __restrict__ beta,
    const int*  __restrict__ n2g,
    unsigned short* __restrict__ h_out,   // [N][64] bf16
    const int* __restrict__ ei,
    int* __restrict__ deg, int* __restrict__ epos,
    int N, int E, int G_film, int G_deg)
{
    const int bid = blockIdx.x;
    const int grp = bid / 3;
    const int rem = bid - grp * 3;
    const int t = threadIdx.x;

    if (rem == 0) {
        // ---------------- deg_count block: 2048 edges, 8 per thread ----------
        const int deg_id = grp;
        if (deg_id >= G_deg) return;
        const int base = deg_id * 2048;
        #pragma unroll
        for (int half = 0; half < 2; ++half) {
            const int e0 = base + half * 1024 + t * 4;
            if (e0 + 3 < E) {
                const int4 d4 = *(const int4*)(ei + E + e0);
                int4 p4;
                p4.x = atomicAdd(&deg[d4.x], 1);
                p4.y = atomicAdd(&deg[d4.y], 1);
                p4.z = atomicAdd(&deg[d4.z], 1);
                p4.w = atomicAdd(&deg[d4.w], 1);
                *(int4*)(epos + e0) = p4;
            } else {
                for (int j = 0; j < 4; ++j) {
                    const int e = e0 + j;
                    if (e < E) epos[e] = atomicAdd(&deg[ei[E + e]], 1);
                }
            }
        }
        return;
    }

    // ---------------- node film block --------------------------------------
    const int film_id = grp * 2 + (rem - 1);
    if (film_id >= G_film) return;
    const int w = t >> 6;
    const int lane = t & 63;
    const int c = lane & 15;
    const int quad = lane >> 4;
    const int n0 = film_id * 64;

    f32x4 c1[4];
    #pragma unroll
    for (int q = 0; q < 4; ++q) { c1[q][0]=0.f; c1[q][1]=0.f; c1[q][2]=0.f; c1[q][3]=0.f; }

    const int mnode = n0 + w * 16 + c;
    const int arow = (mnode < N) ? mnode : (N - 1);
    const float* aptr = nf + (size_t)arow * NODE_DIM + quad * 8;

    #pragma unroll 4
    for (int k0 = 0; k0 < NODE_DIM; k0 += 32) {
        const float4 a01 = *(const float4*)(aptr + k0);
        const float4 a23 = *(const float4*)(aptr + k0 + 4);
        bf16x8 af;
        af[0]=f2bf(a01.x); af[1]=f2bf(a01.y); af[2]=f2bf(a01.z); af[3]=f2bf(a01.w);
        af[4]=f2bf(a23.x); af[5]=f2bf(a23.y); af[6]=f2bf(a23.z); af[7]=f2bf(a23.w);
        #pragma unroll
        for (int nt = 0; nt < 4; ++nt) {
            const bf16x8 bfr = *(const bf16x8*)(fw_bf + ((nt * 16 + c) * NODE_DIM + k0 + quad * 8));
            c1[nt] = __builtin_amdgcn_mfma_f32_16x16x32_bf16(af, bfr, c1[nt], 0, 0, 0);
        }
    }

    #pragma unroll
    for (int nt = 0; nt < 4; ++nt) {
        const float b = film_b[nt * 16 + c];
        c1[nt][0] += b; c1[nt][1] += b; c1[nt][2] += b; c1[nt][3] += b;
    }

    // LN per row (node): row = quad*4 + r, cols spread over 16 lanes x 4 tiles
    float sum[4], sq[4];
    #pragma unroll
    for (int r = 0; r < 4; ++r) {
        sum[r] = c1[0][r] + c1[1][r] + c1[2][r] + c1[3][r];
        sq[r]  = c1[0][r]*c1[0][r] + c1[1][r]*c1[1][r]
               + c1[2][r]*c1[2][r] + c1[3][r]*c1[3][r];
    }
    #pragma unroll
    for (int off = 1; off < 16; off <<= 1) {
        #pragma unroll
        for (int r = 0; r < 4; ++r) {
            sum[r] += __shfl_xor(sum[r], off, 64);
            sq[r]  += __shfl_xor(sq[r],  off, 64);
        }
    }
    float mu[4], inv[4];
    int gid[4];
    #pragma unroll
    for (int r = 0; r < 4; ++r) {
        mu[r] = sum[r] * (1.0f / HID);
        float var = sq[r] * (1.0f / HID) - mu[r] * mu[r];
        var = fmaxf(var, 0.f);
        inv[r] = rsqrtf(var + LN_EPS);
        const int nn = n0 + w * 16 + quad * 4 + r;
        gid[r] = n2g[(nn < N) ? nn : (N - 1)];
    }

    #pragma unroll
    for (int r = 0; r < 4; ++r) {
        const int nn = n0 + w * 16 + quad * 4 + r;
        if (nn >= N) continue;
        #pragma unroll
        for (int nt = 0; nt < 4; ++nt) {
            const int col = nt * 16 + c;
            const float ga = gamma[gid[r] * HID + col];
            const float be = beta[gid[r] * HID + col];
            const float v = fmaxf(ga * ((c1[nt][r] - mu[r]) * inv[r]) + be, 0.f);
            h_out[(size_t)nn * HID + col] = (unsigned short)f2bf(v);
        }
    }
}

// ---------------------------------------------------------------------------
// scan (3 small kernels)
// ---------------------------------------------------------------------------
__global__ __launch_bounds__(1024) void scan1(
    const int* __restrict__ deg, int* __restrict__ csr_off,
    int* __restrict__ bsums, int N)
{
    __shared__ int s[1024];
    const int t = threadIdx.x;
    const int i = blockIdx.x * 1024 + t;
    s[t] = (i < N) ? deg[i] : 0;
    __syncthreads();
    for (int off = 1; off < 1024; off <<= 1) {
        const int x = s[t];
        const int y = (t >= off) ? s[t - off] : 0;
        __syncthreads();
        s[t] = x + y;
        __syncthreads();
    }
    if (i < N) csr_off[i + 1] = s[t];
    if (t == 1023) bsums[blockIdx.x] = s[1023];
}

__global__ __launch_bounds__(1024) void scan2(
    const int* __restrict__ bsums, int* __restrict__ boff, int NB)
{
    __shared__ int s[1024];
    const int t = threadIdx.x;
    const int v = (t < NB) ? bsums[t] : 0;
    s[t] = v;
    __syncthreads();
    for (int off = 1; off < 1024; off <<= 1) {
        const int x = s[t];
        const int y = (t >= off) ? s[t - off] : 0;
        __syncthreads();
        s[t] = x + y;
        __syncthreads();
    }
    if (t < NB) boff[t] = s[t] - v;  // exclusive
}

__global__ __launch_bounds__(1024) void scan3(
    int* __restrict__ csr_off, const int* __restrict__ boff, int N)
{
    const int i = blockIdx.x * 1024 + threadIdx.x;
    if (i < N) csr_off[i + 1] += boff[blockIdx.x];
    if (i == 0) csr_off[0] = 0;
}

// ---------------------------------------------------------------------------
// bucket_fill, 4 edges per thread (int4), atomic-free via epos
// ---------------------------------------------------------------------------
__global__ __launch_bounds__(256) void bucket_fill(
    const int* __restrict__ ei, const int* __restrict__ csr_off,
    const int* __restrict__ epos, int* __restrict__ bucket_src, int E)
{
    const int e0 = (blockIdx.x * 256 + threadIdx.x) * 4;
    if (e0 + 3 < E) {
        const int4 s4 = *(const int4*)(ei + e0);
        const int4 d4 = *(const int4*)(ei + E + e0);
        const int4 p4 = *(const int4*)(epos + e0);
        bucket_src[csr_off[d4.x] + p4.x] = s4.x;
        bucket_src[csr_off[d4.y] + p4.y] = s4.y;
        bucket_src[csr_off[d4.z] + p4.z] = s4.z;
        bucket_src[csr_off[d4.w] + p4.w] = s4.w;
    } else {
        for (int j = 0; j < 4; ++j) {
            const int e = e0 + j;
            if (e < E) bucket_src[csr_off[ei[E + e]] + epos[e]] = ei[e];
        }
    }
}

// ---------------------------------------------------------------------------
// gather-reduce over h rows (128 B = exactly 1 L2 line, fully used).
// Wave: 2 edges x 32 lanes; 4 double-edge loads in flight; shfl_xor(32)
// merges slots. Writes mean_h fp32.
// ---------------------------------------------------------------------------
__global__ __launch_bounds__(256) void edge_aggregate_h(
    const int* __restrict__ csr_off, const int* __restrict__ bucket_src,
    const unsigned int* __restrict__ h,   // [N][32] uints
    float* __restrict__ mean_h, int N)
{
    const int lane = threadIdx.x & 63;
    const int u = lane & 31;      // uint index (2 feats)
    const int eo = lane >> 5;     // edge slot 0..1
    const int d0 = blockIdx.x * 32 + (threadIdx.x >> 6) * 8;

    #pragma unroll 1
    for (int i = 0; i < 8; ++i) {
        const int dst = d0 + i;
        if (dst >= N) return;
        const int base = csr_off[dst];
        const int end  = csr_off[dst + 1];
        float a0 = 0.f, a1 = 0.f;
        for (int p = base; p < end; p += 8) {
            const int e0 = p + eo;
            const int e1 = e0 + 2;
            const int e2 = e0 + 4;
            const int e3 = e0 + 6;
            const int s0 = bucket_src[(e0 < end) ? e0 : (end - 1)];
            const int s1 = bucket_src[(e1 < end) ? e1 : (end - 1)];
            const int s2 = bucket_src[(e2 < end) ? e2 : (end - 1)];
            const int s3 = bucket_src[(e3 < end) ? e3 : (end - 1)];
            const unsigned int v0 = h[(size_t)s0 * 32 + u];
            const unsigned int v1 = h[(size_t)s1 * 32 + u];
            const unsigned int v2 = h[(size_t)s2 * 32 + u];
            const unsigned int v3 = h[(size_t)s3 * 32 + u];
            const float m0 = (e0 < end) ? 1.f : 0.f;
            const float m1 = (e1 < end) ? 1.f : 0.f;
            const float m2 = (e2 < end) ? 1.f : 0.f;
            const float m3 = (e3 < end) ? 1.f : 0.f;
            a0 += m0 * bf_lo(v0) + m1 * bf_lo(v1) + m2 * bf_lo(v2) + m3 * bf_lo(v3);
            a1 += m0 * bf_hi(v0) + m1 * bf_hi(v1) + m2 * bf_hi(v2) + m3 * bf_hi(v3);
        }
        a0 += __shfl_xor(a0, 32, 64);
        a1 += __shfl_xor(a1, 32, 64);
        if (lane < 32) {
            const float d = fmaxf((float)(end - base), 1.f);
            float2 o;
            o.x = a0 / d;
            o.y = a1 / d;
            *(float2*)(mean_h + (size_t)dst * HID + u * 2) = o;
        }
    }
}

// ---------------------------------------------------------------------------
// final linear via MFMA: out = relu(mean_h @ wlinT + lin_b), 0 where deg==0.
// ---------------------------------------------------------------------------
__global__ __launch_bounds__(256) void final_linear(
    const float* __restrict__ mean_h,     // [N][64]
    const short* __restrict__ wlin_bf,    // [128 o][64 k]
    const float* __restrict__ lin_b,
    const int*  __restrict__ csr_off,
    float* __restrict__ out, int N)
{
    const int tid = threadIdx.x;
    const int w = tid >> 6;
    const int lane = tid & 63;
    const int c = lane & 15;
    const int quad = lane >> 4;
    const int n0 = blockIdx.x * 64;

    const int mnode = n0 + w * 16 + c;
    const int arow = (mnode < N) ? mnode : (N - 1);
    const float* aptr = mean_h + (size_t)arow * HID + quad * 8;

    f32x4 c2[8];
    #pragma unroll
    for (int q = 0; q < 8; ++q) { c2[q][0]=0.f; c2[q][1]=0.f; c2[q][2]=0.f; c2[q][3]=0.f; }

    #pragma unroll
    for (int kt = 0; kt < 2; ++kt) {
        const float4 a01 = *(const float4*)(aptr + kt * 32);
        const float4 a23 = *(const float4*)(aptr + kt * 32 + 4);
        bf16x8 af;
        af[0]=f2bf(a01.x); af[1]=f2bf(a01.y); af[2]=f2bf(a01.z); af[3]=f2bf(a01.w);
        af[4]=f2bf(a23.x); af[5]=f2bf(a23.y); af[6]=f2bf(a23.z); af[7]=f2bf(a23.w);
        #pragma unroll
        for (int nt = 0; nt < 8; ++nt) {
            const bf16x8 bfr = *(const bf16x8*)(wlin_bf + (nt * 16 + c) * HID + kt * 32 + quad * 8);
            c2[nt] = __builtin_amdgcn_mfma_f32_16x16x32_bf16(af, bfr, c2[nt], 0, 0, 0);
        }
    }

    float mask[4];
    #pragma unroll
    for (int r = 0; r < 4; ++r) {
        const int nn = n0 + w * 16 + quad * 4 + r;
        const int nc = (nn < N) ? nn : (N - 1);
        mask[r] = (csr_off[nc + 1] - csr_off[nc] > 0) ? 1.f : 0.f;
    }

    #pragma unroll
    for (int nt = 0; nt < 8; ++nt) {
        const float lb = lin_b[nt * 16 + c];
        #pragma unroll
        for (int r = 0; r < 4; ++r) {
            const int nn = n0 + w * 16 + quad * 4 + r;
            if (nn < N)
                out[(size_t)nn * OUT_DIM + nt * 16 + c] =
                    mask[r] * fmaxf(c2[nt][r] + lb, 0.f);
        }
    }
}

extern "C" void kernel_launch(void* const* d_in, const int* in_sizes, int n_in,
                              void* d_out, int out_size, void* d_ws, size_t ws_size,
                              hipStream_t stream) {
    const float* node_feats = (const float*)d_in[0];
    const float* cond_feats = (const float*)d_in[1];
    const float* cond_w_v   = (const float*)d_in[2];
    const float* cond_w_g   = (const float*)d_in[3];
    const float* cond_b     = (const float*)d_in[4];
    const float* film_w     = (const float*)d_in[5];
    const float* film_b     = (const float*)d_in[6];
    const float* lin_w_v    = (const float*)d_in[7];
    const float* lin_w_g    = (const float*)d_in[8];
    const float* lin_b      = (const float*)d_in[9];
    const int* edge_index   = (const int*)d_in[10];
    const int* node2graph   = (const int*)d_in[11];

    const int N = in_sizes[0] / NODE_DIM;     // 100000
    const int B = in_sizes[1] / COND_DIM;     // 64
    const int E = in_sizes[10] / 2;           // 1600000
    const int NB = (N + 1023) / 1024;

    auto align_up = [](size_t x) { return (x + 255) & ~(size_t)255; };
    char* ws = (char*)d_ws;
    size_t off = 0;
    int* deg        = (int*)(ws + off); off += align_up((size_t)N * 4);
    int* csr_off    = (int*)(ws + off); off += align_up((size_t)(N + 1) * 4);
    int* bsums      = (int*)(ws + off); off += align_up(1024 * 4);
    int* boff       = (int*)(ws + off); off += align_up(1024 * 4);
    int* epos       = (int*)(ws + off); off += align_up((size_t)E * 4);
    int* bucket_src = (int*)(ws + off); off += align_up((size_t)E * 4);
    unsigned short* h_buf = (unsigned short*)(ws + off); off += align_up((size_t)N * HID * 2);
    float* mean_h   = (float*)(ws + off); off += align_up((size_t)N * HID * 4);
    float* gamma    = (float*)(ws + off); off += align_up((size_t)B * HID * 4);
    float* beta     = (float*)(ws + off); off += align_up((size_t)B * HID * 4);
    short* wlin_bf  = (short*)(ws + off); off += align_up((size_t)OUT_DIM * HID * 2);
    short* fw_bf    = (short*)(ws + off); off += align_up((size_t)HID * NODE_DIM * 2);

    // prep: 130 work blocks + deg-zero blocks (replaces memset launch)
    prep<<<130 + NB, 256, 0, stream>>>(cond_feats, cond_w_v, cond_w_g, cond_b,
                                       lin_w_v, lin_w_g, film_w,
                                       gamma, beta, wlin_bf, fw_bf, deg, N, B);

    // fused deg_count + node_film, pattern d,f,f
    const int G_film = (N + 63) / 64;
    const int G_deg  = (E + 2047) / 2048;
    const int G_half = (G_film + 1) / 2;
    const int G3 = 3 * ((G_half > G_deg) ? G_half : G_deg);
    fused_phase1<<<G3, 256, 0, stream>>>(
        node_feats, fw_bf, film_b, gamma, beta, node2graph, h_buf,
        edge_index, deg, epos, N, E, G_film, G_deg);

    scan1<<<NB, 1024, 0, stream>>>(deg, csr_off, bsums, N);
    scan2<<<1, 1024, 0, stream>>>(bsums, boff, NB);
    scan3<<<NB, 1024, 0, stream>>>(csr_off, boff, N);
    bucket_fill<<<(E / 4 + 255) / 256, 256, 0, stream>>>(edge_index, csr_off,
                                                         epos, bucket_src, E);

    edge_aggregate_h<<<(N + 31) / 32, 256, 0, stream>>>(
        csr_off, bucket_src, (const unsigned int*)h_buf, mean_h, N);

    final_linear<<<(N + 63) / 64, 256, 0, stream>>>(
        mean_h, wlin_bf, lin_b, csr_off, (float*)d_out, N);
}